// Round 1
// baseline (798.025 us; speedup 1.0000x reference)
//
#include <hip/hip_runtime.h>
#include <hip/hip_bf16.h>

// Problem constants (shapes fixed by the reference):
//   E=8 experts, H=1024, F=4096, TOK=16384 tokens, TPE=2048 tokens/expert.
// Workspace layout (bytes), total 288 MiB:
//   [0,   32M)  xb    : x as bf16            (16384 x 1024)
//   [32M, 96M)  w1t   : w1^T as bf16         (E, 4096, 1024)  (N,K)
//   [96M,160M)  w2t   : w2^T as bf16         (E, 1024, 4096)  (N,K)
//   [160M,288M) inter : gelu(x@w1) as bf16   (E, 2048, 4096)

typedef __attribute__((ext_vector_type(8))) short short8;
typedef __attribute__((ext_vector_type(4))) float floatx4;

// ---------------- fp32 -> bf16 convert (float4 in, ushort4 out) -------------
__global__ __launch_bounds__(256) void cvt_bf16(const float* __restrict__ in,
                                                __hip_bfloat16* __restrict__ out,
                                                int n4) {
  int i = blockIdx.x * 256 + threadIdx.x;
  if (i >= n4) return;
  float4 v = ((const float4*)in)[i];
  union { ushort4 u; __hip_bfloat16 b[4]; } p;
  p.b[0] = __float2bfloat16(v.x);
  p.b[1] = __float2bfloat16(v.y);
  p.b[2] = __float2bfloat16(v.z);
  p.b[3] = __float2bfloat16(v.w);
  ((ushort4*)out)[i] = p.u;
}

// ------------- (E,K,N) fp32 -> (E,N,K) bf16 transpose, 32x32 LDS tile -------
template<int K, int N>
__global__ __launch_bounds__(256) void tpose_bf16(const float* __restrict__ in,
                                                  __hip_bfloat16* __restrict__ out) {
  __shared__ __hip_bfloat16 tile[32][33];  // [k][n], +1 pad
  const size_t eoff = (size_t)blockIdx.z * K * N;
  in += eoff;
  out += eoff;
  const int n0 = blockIdx.x * 32;
  const int k0 = blockIdx.y * 32;
  const int tx = threadIdx.x & 31;   // n within tile (coalesced read)
  const int ty = threadIdx.x >> 5;   // 0..7
#pragma unroll
  for (int i = 0; i < 32; i += 8)
    tile[ty + i][tx] = __float2bfloat16(in[(size_t)(k0 + ty + i) * N + n0 + tx]);
  __syncthreads();
  const int k2 = (threadIdx.x & 15) * 2;  // k pair
  const int nr = threadIdx.x >> 4;        // 0..15
#pragma unroll
  for (int i = 0; i < 32; i += 16) {
    const int n = nr + i;
    union { ushort2 u; __hip_bfloat16 b[2]; } p;
    p.b[0] = tile[k2][n];
    p.b[1] = tile[k2 + 1][n];
    *(ushort2*)&out[(size_t)(n0 + n) * K + k0 + k2] = p.u;
  }
}

// ---------------- m97-structure bf16 GEMM: C = A @ Bt^T ---------------------
// A  : (E, M, K) bf16 row-major
// Bt : (E, N, K) bf16 row-major (i.e. B transposed, K contiguous)
// C  : (E, M, N), bf16 (with fused GeLU) or fp32
// 128x128 tile, BK=32, 256 threads = 4 waves (2x2 of 64x64), 4x4 MFMA/wave.
template<bool GELU, typename OutT>
__global__ __launch_bounds__(256) void gemm_bt(const __hip_bfloat16* __restrict__ A,
                                               const __hip_bfloat16* __restrict__ Bt,
                                               OutT* __restrict__ C,
                                               int M, int N, int K) {
  __shared__ __align__(16) __hip_bfloat16 As[128 * 32];
  __shared__ __align__(16) __hip_bfloat16 Bs[128 * 32];

  const int e = blockIdx.z;
  A  += (size_t)e * M * K;
  Bt += (size_t)e * N * K;
  C  += (size_t)e * M * N;

  const int m0 = blockIdx.y * 128;
  const int n0 = blockIdx.x * 128;
  const int t = threadIdx.x;
  const int lane = t & 63;
  const int l16 = lane & 15;
  const int quad = lane >> 4;
  const int w = t >> 6;
  const int wr = (w >> 1) * 64;  // wave row origin in tile
  const int wc = (w & 1) * 64;   // wave col origin in tile

  floatx4 acc[4][4] = {};

  for (int k0 = 0; k0 < K; k0 += 32) {
    __syncthreads();  // previous tile's LDS reads complete
    // Stage A tile [128][32]: 512 chunks of 8 bf16; lds dest = base + id*16B
    // (wave-uniform base + lane*16 — required by global_load_lds).
#pragma unroll
    for (int i = 0; i < 2; ++i) {
      const int id = t + i * 256;
      const int row = id >> 2;
      const int cc = (id & 3) * 8;
      __builtin_amdgcn_global_load_lds(
          (const __attribute__((address_space(1))) void*)(A + (size_t)(m0 + row) * K + k0 + cc),
          (__attribute__((address_space(3))) void*)(As + id * 8), 16, 0, 0);
    }
    // Stage Bt tile [128][32]
#pragma unroll
    for (int i = 0; i < 2; ++i) {
      const int id = t + i * 256;
      const int row = id >> 2;
      const int cc = (id & 3) * 8;
      __builtin_amdgcn_global_load_lds(
          (const __attribute__((address_space(1))) void*)(Bt + (size_t)(n0 + row) * K + k0 + cc),
          (__attribute__((address_space(3))) void*)(Bs + id * 8), 16, 0, 0);
    }
    __syncthreads();  // drains vmcnt — loads visible

    short8 af[4], bf[4];
#pragma unroll
    for (int i = 0; i < 4; ++i)
      af[i] = *(const short8*)(As + (wr + i * 16 + l16) * 32 + quad * 8);
#pragma unroll
    for (int j = 0; j < 4; ++j)
      bf[j] = *(const short8*)(Bs + (wc + j * 16 + l16) * 32 + quad * 8);
#pragma unroll
    for (int i = 0; i < 4; ++i)
#pragma unroll
      for (int j = 0; j < 4; ++j)
        acc[i][j] = __builtin_amdgcn_mfma_f32_16x16x32_bf16(af[i], bf[j], acc[i][j], 0, 0, 0);
  }

  // Epilogue. C/D layout (verified m89): col = lane&15, row = quad*4 + reg.
#pragma unroll
  for (int i = 0; i < 4; ++i) {
#pragma unroll
    for (int r = 0; r < 4; ++r) {
      const int row = m0 + wr + i * 16 + quad * 4 + r;
      OutT* crow = C + (size_t)row * N + n0 + wc + l16;
#pragma unroll
      for (int j = 0; j < 4; ++j) {
        float v = acc[i][j][r];
        if constexpr (GELU) {
          // jax.nn.gelu default (approximate=True, tanh form)
          float u = 0.7978845608028654f * (v + 0.044715f * v * v * v);
          v = 0.5f * v * (1.0f + tanhf(u));
        }
        if constexpr (sizeof(OutT) == 2)
          crow[j * 16] = __float2bfloat16(v);
        else
          crow[j * 16] = v;
      }
    }
  }
}

extern "C" void kernel_launch(void* const* d_in, const int* in_sizes, int n_in,
                              void* d_out, int out_size, void* d_ws, size_t ws_size,
                              hipStream_t stream) {
  const float* x  = (const float*)d_in[0];   // (16384, 1024)
  const float* w1 = (const float*)d_in[1];   // (8, 1024, 4096)
  const float* w2 = (const float*)d_in[2];   // (8, 4096, 1024)
  // d_in[3] = rows_per_expert (2048) — shapes are baked as constants.
  float* out = (float*)d_out;                // (16384, 1024) fp32

  char* ws = (char*)d_ws;
  __hip_bfloat16* xb    = (__hip_bfloat16*)(ws);
  __hip_bfloat16* w1t   = (__hip_bfloat16*)(ws + (size_t)32 * 1024 * 1024);
  __hip_bfloat16* w2t   = (__hip_bfloat16*)(ws + (size_t)96 * 1024 * 1024);
  __hip_bfloat16* inter = (__hip_bfloat16*)(ws + (size_t)160 * 1024 * 1024);

  // 1) x -> bf16 : 16384*1024 = 16.7M elems, 4 per thread
  cvt_bf16<<<16384, 256, 0, stream>>>(x, xb, 16384 * 1024 / 4);
  // 2) w1 (8,1024,4096) -> w1t (8,4096,1024)
  tpose_bf16<1024, 4096><<<dim3(128, 32, 8), 256, 0, stream>>>(w1, w1t);
  // 3) w2 (8,4096,1024) -> w2t (8,1024,4096)
  tpose_bf16<4096, 1024><<<dim3(32, 128, 8), 256, 0, stream>>>(w2, w2t);
  // 4) inter = gelu(x_e @ w1_e)  : M=2048, N=4096, K=1024 per expert
  gemm_bt<true, __hip_bfloat16>
      <<<dim3(32, 16, 8), 256, 0, stream>>>(xb, w1t, inter, 2048, 4096, 1024);
  // 5) out = inter_e @ w2_e      : M=2048, N=1024, K=4096 per expert
  gemm_bt<false, float>
      <<<dim3(8, 16, 8), 256, 0, stream>>>(inter, w2t, out, 2048, 1024, 4096);
}

// Round 2
// 760.841 us; speedup vs baseline: 1.0489x; 1.0489x over previous
//
#include <hip/hip_runtime.h>
#include <hip/hip_bf16.h>

// Problem constants: E=8 experts, H=1024, F=4096, TOK=16384, TPE=2048.
// Workspace layout (bytes), total 288 MiB:
//   [0,   32M)  xb    : x as bf16            (16384 x 1024)
//   [32M, 96M)  w1t   : w1^T as bf16         (E, 4096, 1024)  (N,K)
//   [96M,160M)  w2t   : w2^T as bf16         (E, 1024, 4096)  (N,K)
//   [160M,288M) inter : gelu(x@w1) as bf16   (E, 2048, 4096)

typedef __attribute__((ext_vector_type(8))) short short8;
typedef __attribute__((ext_vector_type(4))) float floatx4;

static __device__ __forceinline__ ushort f2bf(float f) {
  __hip_bfloat16 h = __float2bfloat16(f);
  return *(ushort*)&h;
}

// ---------------- fp32 -> bf16 convert (float4 in, ushort4 out) -------------
__global__ __launch_bounds__(256) void cvt_bf16(const float* __restrict__ in,
                                                __hip_bfloat16* __restrict__ out,
                                                int n4) {
  int i = blockIdx.x * 256 + threadIdx.x;
  if (i >= n4) return;
  float4 v = ((const float4*)in)[i];
  ushort4 u;
  u.x = f2bf(v.x); u.y = f2bf(v.y); u.z = f2bf(v.z); u.w = f2bf(v.w);
  ((ushort4*)out)[i] = u;
}

// ------------- (E,K,N) fp32 -> (E,N,K) bf16 transpose, 64x64 tile -----------
// Transpose happens on the LDS *write* (ushort2 of k-pairs); both global
// sides and the LDS read are vectorized. Pitch 66 ushorts: LDS write banks
// (4j+i+c)%32 -> 2-way max (free, m136); LDS ds_read_b64 covers all 32 banks.
// Global: reads 256 B/row segments (float4 x16 lanes), writes 128 B/row
// segments (ushort4 x16 lanes).
template<int K, int N>
__global__ __launch_bounds__(256) void tpose_bf16(const float* __restrict__ in,
                                                  __hip_bfloat16* __restrict__ out) {
  __shared__ __align__(16) ushort tile[64][66];  // [n][k]
  const size_t eoff = (size_t)blockIdx.z * (size_t)K * N;
  const int n0 = blockIdx.x * 64;
  const int k0 = blockIdx.y * 64;
  const int t = threadIdx.x;
  const int g = t >> 4;  // 0..15
  const int j = t & 15;  // 0..15
#pragma unroll
  for (int p = 0; p < 2; ++p) {
    const int k = p * 32 + g * 2;  // even k; this thread covers rows k, k+1
    const float4 a = *(const float4*)(in + eoff + (size_t)(k0 + k) * N + n0 + 4 * j);
    const float4 b = *(const float4*)(in + eoff + (size_t)(k0 + k + 1) * N + n0 + 4 * j);
#pragma unroll
    for (int i = 0; i < 4; ++i) {
      ushort2 u;
      u.x = f2bf(((const float*)&a)[i]);
      u.y = f2bf(((const float*)&b)[i]);
      *(ushort2*)&tile[4 * j + i][k] = u;
    }
  }
  __syncthreads();
#pragma unroll
  for (int p = 0; p < 4; ++p) {
    const int n = p * 16 + g;
    const ushort4 u = *(const ushort4*)&tile[n][4 * j];
    *(ushort4*)(out + eoff + (size_t)(n0 + n) * K + k0 + 4 * j) = u;
  }
}

// ---------------- m97-structure bf16 GEMM: C = A @ Bt^T ---------------------
// A  : (E, M, K) bf16 row-major;  Bt : (E, N, K) bf16 row-major (K contig)
// C  : (E, M, N), bf16 (fused fast-GeLU) or fp32
// 128x128 tile, BK=32, 256 threads = 4 waves (2x2 of 64x64), 4x4 MFMA/wave.
template<bool GELU, typename OutT>
__global__ __launch_bounds__(256) void gemm_bt(const __hip_bfloat16* __restrict__ A,
                                               const __hip_bfloat16* __restrict__ Bt,
                                               OutT* __restrict__ C,
                                               int M, int N, int K) {
  __shared__ __align__(16) __hip_bfloat16 As[128 * 32];
  __shared__ __align__(16) __hip_bfloat16 Bs[128 * 32];

  const int e = blockIdx.z;
  A  += (size_t)e * M * K;
  Bt += (size_t)e * N * K;
  C  += (size_t)e * M * N;

  const int m0 = blockIdx.y * 128;
  const int n0 = blockIdx.x * 128;
  const int t = threadIdx.x;
  const int lane = t & 63;
  const int l16 = lane & 15;
  const int quad = lane >> 4;
  const int w = t >> 6;
  const int wr = (w >> 1) * 64;  // wave row origin in tile
  const int wc = (w & 1) * 64;   // wave col origin in tile

  floatx4 acc[4][4] = {};

  for (int k0 = 0; k0 < K; k0 += 32) {
    __syncthreads();  // previous tile's LDS reads complete
#pragma unroll
    for (int i = 0; i < 2; ++i) {
      const int id = t + i * 256;
      const int row = id >> 2;
      const int cc = (id & 3) * 8;
      __builtin_amdgcn_global_load_lds(
          (const __attribute__((address_space(1))) void*)(A + (size_t)(m0 + row) * K + k0 + cc),
          (__attribute__((address_space(3))) void*)(As + id * 8), 16, 0, 0);
    }
#pragma unroll
    for (int i = 0; i < 2; ++i) {
      const int id = t + i * 256;
      const int row = id >> 2;
      const int cc = (id & 3) * 8;
      __builtin_amdgcn_global_load_lds(
          (const __attribute__((address_space(1))) void*)(Bt + (size_t)(n0 + row) * K + k0 + cc),
          (__attribute__((address_space(3))) void*)(Bs + id * 8), 16, 0, 0);
    }
    __syncthreads();  // drains vmcnt — loads visible

    short8 af[4], bf[4];
#pragma unroll
    for (int i = 0; i < 4; ++i)
      af[i] = *(const short8*)(As + (wr + i * 16 + l16) * 32 + quad * 8);
#pragma unroll
    for (int j = 0; j < 4; ++j)
      bf[j] = *(const short8*)(Bs + (wc + j * 16 + l16) * 32 + quad * 8);
#pragma unroll
    for (int i = 0; i < 4; ++i)
#pragma unroll
      for (int j = 0; j < 4; ++j)
        acc[i][j] = __builtin_amdgcn_mfma_f32_16x16x32_bf16(af[i], bf[j], acc[i][j], 0, 0, 0);
  }

  // Epilogue. C/D layout (verified m89): col = lane&15, row = quad*4 + reg.
#pragma unroll
  for (int i = 0; i < 4; ++i) {
#pragma unroll
    for (int r = 0; r < 4; ++r) {
      const int row = m0 + wr + i * 16 + quad * 4 + r;
      OutT* crow = C + (size_t)row * N + n0 + wc + l16;
#pragma unroll
      for (int j = 0; j < 4; ++j) {
        float v = acc[i][j][r];
        if constexpr (GELU) {
          // tanh-gelu via exp: gelu(v) = v - v/(e^{2u}+1), u = 0.7978845608(v+0.044715v^3)
          // e^{2u}=inf -> v - 0 = v (correct limit); v_exp_f32 + v_rcp_f32, no libm tanhf.
          const float u2 = 1.5957691216057308f * (v + 0.044715f * v * v * v);
          const float ex = __expf(u2);
          v = v - v * __builtin_amdgcn_rcpf(ex + 1.0f);
        }
        if constexpr (sizeof(OutT) == 2)
          crow[j * 16] = __float2bfloat16(v);
        else
          crow[j * 16] = v;
      }
    }
  }
}

extern "C" void kernel_launch(void* const* d_in, const int* in_sizes, int n_in,
                              void* d_out, int out_size, void* d_ws, size_t ws_size,
                              hipStream_t stream) {
  const float* x  = (const float*)d_in[0];   // (16384, 1024)
  const float* w1 = (const float*)d_in[1];   // (8, 1024, 4096)
  const float* w2 = (const float*)d_in[2];   // (8, 4096, 1024)
  float* out = (float*)d_out;                // (16384, 1024) fp32

  char* ws = (char*)d_ws;
  __hip_bfloat16* xb    = (__hip_bfloat16*)(ws);
  __hip_bfloat16* w1t   = (__hip_bfloat16*)(ws + (size_t)32 * 1024 * 1024);
  __hip_bfloat16* w2t   = (__hip_bfloat16*)(ws + (size_t)96 * 1024 * 1024);
  __hip_bfloat16* inter = (__hip_bfloat16*)(ws + (size_t)160 * 1024 * 1024);

  // 1) x -> bf16
  cvt_bf16<<<16384, 256, 0, stream>>>(x, xb, 16384 * 1024 / 4);
  // 2) w1 (8,1024,4096) -> w1t (8,4096,1024)
  tpose_bf16<1024, 4096><<<dim3(64, 16, 8), 256, 0, stream>>>(w1, w1t);
  // 3) w2 (8,4096,1024) -> w2t (8,1024,4096)
  tpose_bf16<4096, 1024><<<dim3(16, 64, 8), 256, 0, stream>>>(w2, w2t);
  // 4) inter = gelu(x_e @ w1_e)  : M=2048, N=4096, K=1024 per expert
  gemm_bt<true, __hip_bfloat16>
      <<<dim3(32, 16, 8), 256, 0, stream>>>(xb, w1t, inter, 2048, 4096, 1024);
  // 5) out = inter_e @ w2_e      : M=2048, N=1024, K=4096 per expert
  gemm_bt<false, float>
      <<<dim3(8, 16, 8), 256, 0, stream>>>(inter, w2t, out, 2048, 1024, 4096);
}

// Round 3
// 754.132 us; speedup vs baseline: 1.0582x; 1.0089x over previous
//
#include <hip/hip_runtime.h>
#include <hip/hip_bf16.h>

// Problem constants: E=8 experts, H=1024, F=4096, TOK=16384, TPE=2048.
// Workspace layout (bytes), total 288 MiB:
//   [0,   32M)  xb    : x as bf16            (16384 x 1024)
//   [32M, 96M)  w1t   : w1^T as bf16         (E, 4096, 1024)  (N,K)
//   [96M,160M)  w2t   : w2^T as bf16         (E, 1024, 4096)  (N,K)
//   [160M,288M) inter : gelu(x@w1) as bf16   (E, 2048, 4096)

typedef __attribute__((ext_vector_type(8))) short short8;
typedef __attribute__((ext_vector_type(4))) float floatx4;

static __device__ __forceinline__ ushort f2bf(float f) {
  __hip_bfloat16 h = __float2bfloat16(f);
  return *(ushort*)&h;
}

// XOR swizzle for the transpose LDS tile: chunk o of row n lives at chunk slot
// s. Makes both ds_write_b128 (write phase: o in {0,1} per wave) and
// ds_read_b128 (read phase: c 0..7 per 8-lane row group) spread across all
// 32 banks. Same formula must be used on both sides.
static __device__ __forceinline__ int swz(int n, int o) {
  return o ^ (n & 7) ^ ((n >> 3) & 7);
}

// ---- transpose one 128(n) x 64(k) tile: fp32 (K,N) -> bf16 (N,K) -----------
// Read:  8 rows/thread, float4/lane -> 256 B segments per 16-lane group.
// LDS:   ushort[128][64], 16 B chunks, XOR-swizzled; all b128 ops, 16-B aligned.
// Write: ushort8 (16 B)/lane, 8 lanes/row -> 128 B segments.
template<int K, int N>
static __device__ __forceinline__ void tpose_tile(const float* __restrict__ in,
                                                  __hip_bfloat16* __restrict__ out,
                                                  ushort* lds, int e, int nt, int kt) {
  const size_t eoff = (size_t)e * K * N;
  const int n0 = nt * 128, k0 = kt * 64;
  const int t = threadIdx.x;
  const int j = t & 15;
  const int g = t >> 4;   // 0..15
  const int o = g >> 1;   // 0..7  k-octet (rows k0+8o .. k0+8o+7)
  const int h = g & 1;    // 0..1  n-half
  const float* src = in + eoff + (size_t)(k0 + 8 * o) * N + n0 + h * 64 + 4 * j;
  float4 v[8];
#pragma unroll
  for (int r = 0; r < 8; ++r)
    v[r] = *(const float4*)(src + (size_t)r * N);
#pragma unroll
  for (int i = 0; i < 4; ++i) {
    const int n = h * 64 + 4 * j + i;
    union { short8 s8; ushort u[8]; } p;
#pragma unroll
    for (int r = 0; r < 8; ++r)
      p.u[r] = f2bf(((const float*)&v[r])[i]);
    *(short8*)(lds + n * 64 + swz(n, o) * 8) = p.s8;
  }
  __syncthreads();
  const int c = t & 7;     // k-chunk
  const int r0 = t >> 3;   // 0..31 row within pass
#pragma unroll
  for (int p = 0; p < 4; ++p) {
    const int n = p * 32 + r0;
    short8 u = *(const short8*)(lds + n * 64 + swz(n, c) * 8);
    *(short8*)(out + eoff + (size_t)(n0 + n) * K + k0 + 8 * c) = u;
  }
}

// ---- fp32 -> bf16 streaming convert: 8 float4 / thread ---------------------
static __device__ __forceinline__ void cvt_part(const float* __restrict__ x,
                                                __hip_bfloat16* __restrict__ xb, int b) {
  const int t = threadIdx.x;
  const float4* src = (const float4*)x + (size_t)b * 2048 + t;
  ushort4* dst = (ushort4*)xb + (size_t)b * 2048 + t;
#pragma unroll
  for (int u = 0; u < 8; ++u) {
    float4 v = src[u * 256];
    ushort4 q;
    q.x = f2bf(v.x); q.y = f2bf(v.y); q.z = f2bf(v.z); q.w = f2bf(v.w);
    dst[u * 256] = q;
  }
}

// ---- merged prep: one launch for cvt(x) + tpose(w1) + tpose(w2) ------------
// blocks [0,2048)      : cvt x (16384x1024)
// blocks [2048,6144)   : tpose w1 (E=8, K=1024, N=4096): 512 tiles/expert
// blocks [6144,10240)  : tpose w2 (E=8, K=4096, N=1024): 512 tiles/expert
__global__ __launch_bounds__(256) void prep(const float* __restrict__ x,
                                            const float* __restrict__ w1,
                                            const float* __restrict__ w2,
                                            __hip_bfloat16* __restrict__ xb,
                                            __hip_bfloat16* __restrict__ w1t,
                                            __hip_bfloat16* __restrict__ w2t) {
  __shared__ __align__(16) ushort lds[128 * 64];
  const int b = blockIdx.x;
  if (b < 2048) {
    cvt_part(x, xb, b);
  } else if (b < 6144) {
    const int bb = b - 2048;  // e*512 + kt*32 + nt
    tpose_tile<1024, 4096>(w1, w1t, lds, bb >> 9, bb & 31, (bb >> 5) & 15);
  } else {
    const int bb = b - 6144;  // e*512 + kt*8 + nt
    tpose_tile<4096, 1024>(w2, w2t, lds, bb >> 9, bb & 7, (bb >> 3) & 63);
  }
}

// ---------------- m97-structure bf16 GEMM: C = A @ Bt^T ---------------------
// A  : (E, M, K) bf16 row-major;  Bt : (E, N, K) bf16 row-major (K contig)
// C  : (E, M, N), bf16 (fused fast-GeLU) or fp32
// 128x128 tile, BK=32, 256 threads = 4 waves (2x2 of 64x64), 4x4 MFMA/wave.
template<bool GELU, typename OutT>
__global__ __launch_bounds__(256) void gemm_bt(const __hip_bfloat16* __restrict__ A,
                                               const __hip_bfloat16* __restrict__ Bt,
                                               OutT* __restrict__ C,
                                               int M, int N, int K) {
  __shared__ __align__(16) __hip_bfloat16 As[128 * 32];
  __shared__ __align__(16) __hip_bfloat16 Bs[128 * 32];

  const int e = blockIdx.z;
  A  += (size_t)e * M * K;
  Bt += (size_t)e * N * K;
  C  += (size_t)e * M * N;

  const int m0 = blockIdx.y * 128;
  const int n0 = blockIdx.x * 128;
  const int t = threadIdx.x;
  const int lane = t & 63;
  const int l16 = lane & 15;
  const int quad = lane >> 4;
  const int w = t >> 6;
  const int wr = (w >> 1) * 64;  // wave row origin in tile
  const int wc = (w & 1) * 64;   // wave col origin in tile

  floatx4 acc[4][4] = {};

  for (int k0 = 0; k0 < K; k0 += 32) {
    __syncthreads();  // previous tile's LDS reads complete
#pragma unroll
    for (int i = 0; i < 2; ++i) {
      const int id = t + i * 256;
      const int row = id >> 2;
      const int cc = (id & 3) * 8;
      __builtin_amdgcn_global_load_lds(
          (const __attribute__((address_space(1))) void*)(A + (size_t)(m0 + row) * K + k0 + cc),
          (__attribute__((address_space(3))) void*)(As + id * 8), 16, 0, 0);
    }
#pragma unroll
    for (int i = 0; i < 2; ++i) {
      const int id = t + i * 256;
      const int row = id >> 2;
      const int cc = (id & 3) * 8;
      __builtin_amdgcn_global_load_lds(
          (const __attribute__((address_space(1))) void*)(Bt + (size_t)(n0 + row) * K + k0 + cc),
          (__attribute__((address_space(3))) void*)(Bs + id * 8), 16, 0, 0);
    }
    __syncthreads();  // drains vmcnt — loads visible

    short8 af[4], bf[4];
#pragma unroll
    for (int i = 0; i < 4; ++i)
      af[i] = *(const short8*)(As + (wr + i * 16 + l16) * 32 + quad * 8);
#pragma unroll
    for (int j = 0; j < 4; ++j)
      bf[j] = *(const short8*)(Bs + (wc + j * 16 + l16) * 32 + quad * 8);
#pragma unroll
    for (int i = 0; i < 4; ++i)
#pragma unroll
      for (int j = 0; j < 4; ++j)
        acc[i][j] = __builtin_amdgcn_mfma_f32_16x16x32_bf16(af[i], bf[j], acc[i][j], 0, 0, 0);
  }

  // Epilogue. C/D layout (verified m89): col = lane&15, row = quad*4 + reg.
#pragma unroll
  for (int i = 0; i < 4; ++i) {
#pragma unroll
    for (int r = 0; r < 4; ++r) {
      const int row = m0 + wr + i * 16 + quad * 4 + r;
      OutT* crow = C + (size_t)row * N + n0 + wc + l16;
#pragma unroll
      for (int j = 0; j < 4; ++j) {
        float v = acc[i][j][r];
        if constexpr (GELU) {
          // tanh-gelu via exp: gelu(v) = v - v/(e^{2u}+1), u = 0.7978845608(v+0.044715v^3)
          const float u2 = 1.5957691216057308f * (v + 0.044715f * v * v * v);
          const float ex = __expf(u2);
          v = v - v * __builtin_amdgcn_rcpf(ex + 1.0f);
        }
        if constexpr (sizeof(OutT) == 2)
          crow[j * 16] = __float2bfloat16(v);
        else
          crow[j * 16] = v;
      }
    }
  }
}

extern "C" void kernel_launch(void* const* d_in, const int* in_sizes, int n_in,
                              void* d_out, int out_size, void* d_ws, size_t ws_size,
                              hipStream_t stream) {
  const float* x  = (const float*)d_in[0];   // (16384, 1024)
  const float* w1 = (const float*)d_in[1];   // (8, 1024, 4096)
  const float* w2 = (const float*)d_in[2];   // (8, 4096, 1024)
  float* out = (float*)d_out;                // (16384, 1024) fp32

  char* ws = (char*)d_ws;
  __hip_bfloat16* xb    = (__hip_bfloat16*)(ws);
  __hip_bfloat16* w1t   = (__hip_bfloat16*)(ws + (size_t)32 * 1024 * 1024);
  __hip_bfloat16* w2t   = (__hip_bfloat16*)(ws + (size_t)96 * 1024 * 1024);
  __hip_bfloat16* inter = (__hip_bfloat16*)(ws + (size_t)160 * 1024 * 1024);

  // 1) prep: x->bf16, w1->w1t (bf16, transposed), w2->w2t (bf16, transposed)
  prep<<<10240, 256, 0, stream>>>(x, w1, w2, xb, w1t, w2t);
  // 2) inter = gelu(x_e @ w1_e)  : M=2048, N=4096, K=1024 per expert
  gemm_bt<true, __hip_bfloat16>
      <<<dim3(32, 16, 8), 256, 0, stream>>>(xb, w1t, inter, 2048, 4096, 1024);
  // 3) out = inter_e @ w2_e      : M=2048, N=1024, K=4096 per expert
  gemm_bt<false, float>
      <<<dim3(8, 16, 8), 256, 0, stream>>>(inter, w2t, out, 2048, 1024, 4096);
}